// Round 1
// 98.128 us; speedup vs baseline: 1.0715x; 1.0715x over previous
//
#include <hip/hip_runtime.h>

// Problem constants
#define NLAYER 4
#define BB 4
#define LL 512
#define DD 768
#define NLIN 128
#define NENT 10

// Workspace layout (in floats):
//   weff   : [20][768] at offset 0        c-major! c<10: w_i-effective, c>=10: w_j-effective
//   constc : [16]      at offset 15360    (b_span . w_cls[c] + b_cls[c])
//   si     : [40][512] at offset 15376    (si[b*10+c][i], constc folded in)
//   sj     : [40][512] at offset 35856
#define OFF_CONST 15360
#define OFF_SI    15376
#define OFF_SJ    35856

typedef float vfloat4 __attribute__((ext_vector_type(4)));

// ---------------------------------------------------------------------------
// Kernel A: fuse w_cls through w_span -> weff[20][768] (c-major), + constc.
// weff[c][d]      = sum_o w_cls[c][o] * w_span[o][d]        (c in 0..9)
// weff[10+c][d]   = sum_o w_cls[c][o] * w_span[o][768 + d]
// 4-way o-split across consecutive lanes: 32 MACs/thread + shfl reduce.
// 61480 threads -> 241 blocks (was 60) -> 4x the latency-hiding parallelism.
// ---------------------------------------------------------------------------
__global__ void __launch_bounds__(256) fuse_weights(
    const float* __restrict__ w_span,
    const float* __restrict__ b_span,
    const float* __restrict__ w_cls,
    const float* __restrict__ b_cls,
    float* __restrict__ ws)
{
    const int t   = blockIdx.x * 256 + threadIdx.x;
    const int sub = t & 3;          // o-chunk: o in [sub*32, sub*32+32)
    const int idx = t >> 2;         // output index 0..15369
    float* weff   = ws;
    float* constc = ws + OFF_CONST;

    if (idx < 20 * DD) {
        const int c2 = idx / DD;          // 0..19
        const int d  = idx - c2 * DD;     // consecutive across lane groups -> coalesced
        const int ci   = (c2 < NENT) ? c2 : c2 - NENT;
        const int half = (c2 < NENT) ? 0  : 1;
        const float* wc    = w_cls + ci * NLIN + sub * 32;
        const float* wsrow = w_span + (size_t)sub * 32 * (2 * DD) + half * DD + d;
        float acc = 0.f;
        #pragma unroll
        for (int o = 0; o < 32; ++o)
            acc += wc[o] * wsrow[(size_t)o * (2 * DD)];
        // reduce the 4 o-chunks (lanes 4k..4k+3 share idx)
        acc += __shfl_xor(acc, 1, 64);
        acc += __shfl_xor(acc, 2, 64);
        if (sub == 0) weff[c2 * DD + d] = acc;    // c-major, coalesced store
    } else if (idx < 20 * DD + NENT) {
        const int c = idx - 20 * DD;
        const float* wc = w_cls + c * NLIN + sub * 32;
        const float* bs = b_span + sub * 32;
        float cc = (sub == 0) ? b_cls[c] : 0.f;
        #pragma unroll
        for (int o = 0; o < 32; ++o) cc += bs[o] * wc[o];
        cc += __shfl_xor(cc, 1, 64);
        cc += __shfl_xor(cc, 2, 64);
        if (sub == 0) constc[c] = cc;
    }
}

// ---------------------------------------------------------------------------
// Kernel B: tok = sum over 4 layers; si/sj = tok @ weff^T.
// One wave per (b,l) row: 2048 rows = 512 blocks x 4 waves.
// Load-order change vs previous version: issue the 15 staging loads FIRST,
// then the 12 hs loads (nontemporal, stream-once), then ds_write + barrier.
// vmcnt is in-order, so ds_writes proceed at vmcnt(12) while hs is still in
// flight -> HBM latency hides under staging + barrier instead of being
// exposed after it.
// ---------------------------------------------------------------------------
__global__ void __launch_bounds__(256) reduce_proj(
    const float* __restrict__ hs,
    const float* __restrict__ wsro,
    float* __restrict__ si,
    float* __restrict__ sj)
{
    __shared__ float wsh[20 * DD];   // 61440 B -> 2 blocks/CU (all 512 blocks resident)

    const int tid  = threadIdx.x;
    const int wave = (blockIdx.x * 256 + tid) >> 6;  // 0..2047
    const int lane = tid & 63;
    const int b = wave >> 9;
    const int l = wave & 511;

    const size_t LAYER_STRIDE = (size_t)BB * LL * DD;   // 1,572,864
    const size_t base = (size_t)(b * LL + l) * DD;

    // 1) issue staging loads (oldest in the vmcnt queue)
    const vfloat4* src = (const vfloat4*)wsro;
    vfloat4 stg[15];
    #pragma unroll
    for (int r = 0; r < 15; ++r)
        stg[r] = src[r * 256 + tid];

    // 2) issue hs loads (newest; nontemporal: hs is read exactly once)
    vfloat4 t0[3], t1[3], t2[3], t3[3];
    #pragma unroll
    for (int k = 0; k < 3; ++k) {
        const float* hp = hs + base + k * 256 + lane * 4;   // 16B-aligned, coalesced
        t0[k] = __builtin_nontemporal_load((const vfloat4*)(hp));
        t1[k] = __builtin_nontemporal_load((const vfloat4*)(hp + LAYER_STRIDE));
        t2[k] = __builtin_nontemporal_load((const vfloat4*)(hp + 2 * LAYER_STRIDE));
        t3[k] = __builtin_nontemporal_load((const vfloat4*)(hp + 3 * LAYER_STRIDE));
    }

    // 3) LDS write (waits only for staging loads, hs still in flight)
    vfloat4* dst = (vfloat4*)wsh;
    #pragma unroll
    for (int r = 0; r < 15; ++r)
        dst[r * 256 + tid] = stg[r];
    __syncthreads();

    float acc[20];
    #pragma unroll
    for (int c = 0; c < 20; ++c) acc[c] = 0.f;

    #pragma unroll
    for (int k = 0; k < 3; ++k) {
        vfloat4 tv = t0[k] + t1[k] + t2[k] + t3[k];
        const float* wbase = wsh + k * 256 + lane * 4;       // + c*768 per channel
        #pragma unroll
        for (int c = 0; c < 20; ++c) {
            vfloat4 w = *(const vfloat4*)(wbase + c * DD);   // ds_read_b128, conflict-free
            acc[c] += tv.x * w.x + tv.y * w.y + tv.z * w.z + tv.w * w.w;
        }
    }

    // Butterfly reduce each of the 20 partials across the wave (64 lanes)
    #pragma unroll
    for (int c = 0; c < 20; ++c) {
        float v = acc[c];
        v += __shfl_xor(v, 1,  64);
        v += __shfl_xor(v, 2,  64);
        v += __shfl_xor(v, 4,  64);
        v += __shfl_xor(v, 8,  64);
        v += __shfl_xor(v, 16, 64);
        v += __shfl_xor(v, 32, 64);
        acc[c] = v;
    }

    if (lane == 0) {
        const float* constc = wsro + OFF_CONST;
        const int rb = b * NENT;
        #pragma unroll
        for (int c = 0; c < NENT; ++c) {
            si[(rb + c) * LL + l] = acc[c] + constc[c];   // fold const into si
            sj[(rb + c) * LL + l] = acc[10 + c];
        }
    }
}

// ---------------------------------------------------------------------------
// Kernel C: out[b][c][i][j] = si[b*10+c][i] + sj[b*10+c][j]
// float4 over j; nontemporal stores (output is write-once, never re-read ->
// keep L2 clean for si/sj broadcast reads).
// ---------------------------------------------------------------------------
__global__ void __launch_bounds__(256) fill_out(
    const float* __restrict__ si,
    const float* __restrict__ sj,
    float* __restrict__ out)
{
    const int idx4 = blockIdx.x * 256 + threadIdx.x;     // exact grid, no bounds check
    const int j4 = idx4 & 127;          // j/4
    const int i  = (idx4 >> 7) & 511;
    const int bc = idx4 >> 16;          // b*10+c, 0..39
    const float   s = si[bc * LL + i];
    const vfloat4 v = ((const vfloat4*)(sj + bc * LL))[j4];
    vfloat4 o = v + s;
    __builtin_nontemporal_store(o, ((vfloat4*)out) + idx4);
}

extern "C" void kernel_launch(void* const* d_in, const int* in_sizes, int n_in,
                              void* d_out, int out_size, void* d_ws, size_t ws_size,
                              hipStream_t stream) {
    const float* hs     = (const float*)d_in[0];  // (4,4,512,768)
    const float* w_span = (const float*)d_in[1];  // (128,1536)
    const float* b_span = (const float*)d_in[2];  // (128,)
    const float* w_cls  = (const float*)d_in[3];  // (10,128)
    const float* b_cls  = (const float*)d_in[4];  // (10,)
    float* ws  = (float*)d_ws;
    float* out = (float*)d_out;
    float* si = ws + OFF_SI;
    float* sj = ws + OFF_SJ;

    // (15370 outputs x 4 o-chunks + pad) / 256 = 241 blocks
    fuse_weights<<<241, 256, 0, stream>>>(w_span, b_span, w_cls, b_cls, ws);
    reduce_proj<<<512, 256, 0, stream>>>(hs, ws, si, sj);
    // 2,621,440 float4 elements / 256 = 10240 blocks, exact
    fill_out<<<10240, 256, 0, stream>>>(si, sj, out);
}